// Round 2
// baseline (609.426 us; speedup 1.0000x reference)
//
#include <hip/hip_runtime.h>
#include <math.h>

#define DIMN 2048
#define HDIM 256
#define NSIG 6
#define NHEADS 4
#define HEADDIM 64
#define SWHID 4096
#define BB 4
#define SSEQ 2048
#define EPSF 1e-6f

__device__ __forceinline__ float wsum(float v) {
    #pragma unroll
    for (int m = 1; m < 64; m <<= 1) v += __shfl_xor(v, m, 64);
    return v;
}

__device__ __forceinline__ float dot4(float4 a, float4 b) {
    return a.x*b.x + a.y*b.y + a.z*b.z + a.w*b.w;
}

// kA: fused scalar front-end (single block):
//   signals -> confidence head -> (A,C) rank-1 fold of signal_proj into in_proj
//   -> 6-token multihead attention -> token mean -> out-proj => us[4][256]
__global__ __launch_bounds__(256) void kA_front(
    const float* __restrict__ epi, const float* __restrict__ ale,
    const float* __restrict__ ood, const float* __restrict__ cunc,
    const float* __restrict__ ece, const float* __restrict__ moral,
    const float* __restrict__ ipw, const float* __restrict__ ipb,
    const float* __restrict__ spw, const float* __restrict__ spb,
    const float* __restrict__ chw1, const float* __restrict__ chb1,
    const float* __restrict__ chw2, const float* __restrict__ chb2,
    const float* __restrict__ outw, const float* __restrict__ outb,
    float* __restrict__ us, float* __restrict__ out_conf,
    float* __restrict__ out_sig, float* __restrict__ accum)
{
    __shared__ float sSig[BB][NSIG];
    __shared__ float sA[768], sC[768];
    __shared__ float sQKV[NSIG][768];
    __shared__ float sAtt[NHEADS * NSIG][NSIG];
    __shared__ float sObar[BB][HDIM];
    __shared__ float sRedW[BB][4];
    int t = threadIdx.x, wv = t >> 6, lane = t & 63;

    if (t < 8) accum[t] = 0.f;

    // --- signals: wave wv handles batch b = wv ---
    {
        int b = wv;
        float e = epi[b * 64 + lane];
        float a = ale[b * 64 + lane];
        float se = wsum(e) * (1.f / 64.f);
        float sa = wsum(a) * (1.f / 64.f);
        if (lane == 0) {
            sSig[b][0] = se; sSig[b][1] = sa;
            sSig[b][2] = ood[b]; sSig[b][3] = cunc[b];
            sSig[b][4] = ece[0]; sSig[b][5] = moral[b];
            for (int k = 0; k < NSIG; k++) out_sig[b * NSIG + k] = sSig[b][k];
        }
    }

    // --- A,C fold: A[r]=dot(ipw[r],sp_w), C[r]=dot(ipw[r],sp_b)+ipb[r] ---
    {
        float4 spw4 = ((const float4*)spw)[lane];
        float4 spb4 = ((const float4*)spb)[lane];
        for (int r = wv; r < 768; r += 4) {
            float4 w = ((const float4*)(ipw + (size_t)r * HDIM))[lane];
            float aa = wsum(dot4(w, spw4));
            float cc = wsum(dot4(w, spb4));
            if (lane == 0) { sA[r] = aa; sC[r] = cc + ipb[r]; }
        }
    }
    __syncthreads();

    // --- confidence head: Linear(6,256) -> GELU(exact) -> Linear(256,1) -> sigmoid ---
    {
        float c1[NSIG];
        #pragma unroll
        for (int j = 0; j < NSIG; j++) c1[j] = chw1[t * NSIG + j];
        float cb = chb1[t], cw2 = chw2[t];
        #pragma unroll
        for (int b = 0; b < BB; b++) {
            float z = cb;
            #pragma unroll
            for (int j = 0; j < NSIG; j++) z += sSig[b][j] * c1[j];
            float g = 0.5f * z * (1.f + erff(z * 0.70710678118654752f));
            float v = wsum(g * cw2);
            if (lane == 0) sRedW[b][wv] = v;
        }
    }
    __syncthreads();
    if (t < BB) {
        float s = sRedW[t][0] + sRedW[t][1] + sRedW[t][2] + sRedW[t][3] + chb2[0];
        out_conf[t] = 1.f / (1.f + expf(-s));
    }

    // --- attention over the 6 signal tokens, per batch ---
    for (int b = 0; b < BB; b++) {
        for (int idx = t; idx < NSIG * 768; idx += 256) {
            int j = idx / 768, r = idx - j * 768;
            sQKV[j][r] = sSig[b][j] * sA[r] + sC[r];
        }
        __syncthreads();
        if (t < NHEADS * NSIG) {
            int h = t / NSIG, qi = t - h * NSIG;
            float sc[NSIG]; float mx = -1e30f;
            for (int ki = 0; ki < NSIG; ki++) {
                float s = 0;
                for (int d = 0; d < HEADDIM; d++)
                    s += sQKV[qi][h*64 + d] * sQKV[ki][256 + h*64 + d];
                s *= 0.125f;
                sc[ki] = s; mx = fmaxf(mx, s);
            }
            float den = 0;
            for (int ki = 0; ki < NSIG; ki++) { sc[ki] = expf(sc[ki] - mx); den += sc[ki]; }
            float inv = 1.f / den;
            for (int ki = 0; ki < NSIG; ki++) sAtt[t][ki] = sc[ki] * inv;
        }
        __syncthreads();
        {
            int m = t, h = m >> 6;
            float ob = 0;
            for (int qi = 0; qi < NSIG; qi++) {
                float o = 0;
                #pragma unroll
                for (int ki = 0; ki < NSIG; ki++)
                    o += sAtt[h * NSIG + qi][ki] * sQKV[ki][512 + m];
                ob += o;
            }
            sObar[b][m] = ob * (1.f / 6.f);  // mean over tokens (out-proj is linear)
        }
        __syncthreads();
    }

    // --- out-proj: us[b][m] = dot(sObar[b], out_w[m,:]) + out_b[m] ---
    {
        float4 ob4[BB];
        #pragma unroll
        for (int b = 0; b < BB; b++) ob4[b] = ((const float4*)sObar[b])[lane];
        for (int m = wv; m < HDIM; m += 4) {
            float4 w = ((const float4*)(outw + (size_t)m * HDIM))[lane];
            float acc[BB];
            #pragma unroll
            for (int b = 0; b < BB; b++) acc[b] = wsum(dot4(w, ob4[b]));
            if (lane == 0) {
                float o = outb[m];
                #pragma unroll
                for (int b = 0; b < BB; b++) us[b * HDIM + m] = acc[b] + o;
            }
        }
    }
}

// K2: t1n[b][d] = (dot(us[b], sum_w1[d,:]) + sum_b1[d]) * rms1_w[d]; accum[b] += pre^2
__global__ __launch_bounds__(256) void k2_sumproj(
    const float* __restrict__ us, const float* __restrict__ w1,
    const float* __restrict__ b1, const float* __restrict__ rw1,
    float* __restrict__ t1n, float* __restrict__ accum)
{
    __shared__ float bsq[BB];
    int t = threadIdx.x, wv = t >> 6, lane = t & 63;
    if (t < BB) bsq[t] = 0.f;
    __syncthreads();
    int d = blockIdx.x * 4 + wv;
    float4 w = ((const float4*)(w1 + (size_t)d * HDIM))[lane];
    float acc[BB];
    #pragma unroll
    for (int b = 0; b < BB; b++) {
        float4 u = ((const float4*)(us + b * HDIM))[lane];
        acc[b] = dot4(w, u);
    }
    #pragma unroll
    for (int b = 0; b < BB; b++) acc[b] = wsum(acc[b]);
    if (lane == 0) {
        #pragma unroll
        for (int b = 0; b < BB; b++) {
            float v = acc[b] + b1[d];
            atomicAdd(&bsq[b], v * v);
            t1n[b * DIMN + d] = v * rw1[d];
        }
    }
    __syncthreads();
    if (t < BB) atomicAdd(&accum[t], bsq[t]);
}

// K3: h[b][j] = silu(s1*dot(t1n[b], sw_w1[j,:])) * (s1*dot(t1n[b], sw_w3[j,:]))
__global__ __launch_bounds__(256) void k3_swiglu(
    const float* __restrict__ t1n, const float* __restrict__ sw1,
    const float* __restrict__ sw3, const float* __restrict__ accum,
    float* __restrict__ h)
{
    __shared__ __align__(16) float sT[BB * DIMN];
    int t = threadIdx.x, wv = t >> 6, lane = t & 63;
    #pragma unroll
    for (int k = 0; k < 8; k++)
        ((float4*)sT)[k * 256 + t] = ((const float4*)t1n)[k * 256 + t];
    __syncthreads();
    int j = blockIdx.x * 4 + wv;
    const float4* r1 = (const float4*)(sw1 + (size_t)j * DIMN);
    const float4* r3 = (const float4*)(sw3 + (size_t)j * DIMN);
    float acc1[BB] = {0,0,0,0}, acc3[BB] = {0,0,0,0};
    #pragma unroll
    for (int it = 0; it < 8; it++) {
        float4 w1 = r1[it * 64 + lane];
        float4 w3 = r3[it * 64 + lane];
        #pragma unroll
        for (int b = 0; b < BB; b++) {
            float4 tv = ((const float4*)(sT + b * DIMN))[it * 64 + lane];
            acc1[b] += dot4(w1, tv);
            acc3[b] += dot4(w3, tv);
        }
    }
    #pragma unroll
    for (int b = 0; b < BB; b++) { acc1[b] = wsum(acc1[b]); acc3[b] = wsum(acc3[b]); }
    if (lane == 0) {
        #pragma unroll
        for (int b = 0; b < BB; b++) {
            float s = rsqrtf(accum[b] * (1.f / DIMN) + EPSF);
            float a = acc1[b] * s;
            float sil = a / (1.f + expf(-a));
            h[b * SWHID + j] = sil * (acc3[b] * s);
        }
    }
}

// K4: t2[b][d] = dot(h[b], sw_w2[d,:])
__global__ __launch_bounds__(256) void k4_down(
    const float* __restrict__ h, const float* __restrict__ sw2,
    float* __restrict__ t2)
{
    __shared__ __align__(16) float sH[BB * SWHID];  // 64 KiB
    int t = threadIdx.x, wv = t >> 6, lane = t & 63;
    #pragma unroll
    for (int k = 0; k < 16; k++)
        ((float4*)sH)[k * 256 + t] = ((const float4*)h)[k * 256 + t];
    __syncthreads();
    int d = blockIdx.x * 4 + wv;
    const float4* wr = (const float4*)(sw2 + (size_t)d * SWHID);
    float acc[BB] = {0,0,0,0};
    #pragma unroll
    for (int it = 0; it < 16; it++) {
        float4 w = wr[it * 64 + lane];
        #pragma unroll
        for (int b = 0; b < BB; b++) {
            float4 hv = ((const float4*)(sH + b * SWHID))[it * 64 + lane];
            acc[b] += dot4(w, hv);
        }
    }
    #pragma unroll
    for (int b = 0; b < BB; b++) acc[b] = wsum(acc[b]);
    if (lane == 0) {
        #pragma unroll
        for (int b = 0; b < BB; b++) t2[b * DIMN + d] = acc[b];
    }
}

// K5: t3n[b][d] = (dot(t2[b], sum_w2[d,:]) + sum_b2[d]) * rms2_w[d]; accum[4+b] += pre^2
__global__ __launch_bounds__(256) void k5_out(
    const float* __restrict__ t2, const float* __restrict__ w2,
    const float* __restrict__ b2, const float* __restrict__ rw2,
    float* __restrict__ t3n, float* __restrict__ accum)
{
    __shared__ __align__(16) float sT[BB * DIMN];
    __shared__ float bsq[BB];
    int t = threadIdx.x, wv = t >> 6, lane = t & 63;
    if (t < BB) bsq[t] = 0.f;
    #pragma unroll
    for (int k = 0; k < 8; k++)
        ((float4*)sT)[k * 256 + t] = ((const float4*)t2)[k * 256 + t];
    __syncthreads();
    int d = blockIdx.x * 4 + wv;
    const float4* wr = (const float4*)(w2 + (size_t)d * DIMN);
    float acc[BB] = {0,0,0,0};
    #pragma unroll
    for (int it = 0; it < 8; it++) {
        float4 w = wr[it * 64 + lane];
        #pragma unroll
        for (int b = 0; b < BB; b++) {
            float4 tv = ((const float4*)(sT + b * DIMN))[it * 64 + lane];
            acc[b] += dot4(w, tv);
        }
    }
    #pragma unroll
    for (int b = 0; b < BB; b++) acc[b] = wsum(acc[b]);
    if (lane == 0) {
        #pragma unroll
        for (int b = 0; b < BB; b++) {
            float v = acc[b] + b2[d];
            atomicAdd(&bsq[b], v * v);
            t3n[b * DIMN + d] = v * rw2[d];
        }
    }
    __syncthreads();
    if (t < BB) atomicAdd(&accum[4 + t], bsq[t]);
}

// K7: one wave per token row. e = t3n*scale2 (= unc_embedding), y = x + 0.05*e,
//     x_aware = rmsnorm(y)*norm_w. No LDS, no __syncthreads.
__global__ __launch_bounds__(256) void k7_final(
    const float* __restrict__ x, const float* __restrict__ t3n,
    const float* __restrict__ accum, const float* __restrict__ nw,
    float* __restrict__ xa, float* __restrict__ ue)
{
    int t = threadIdx.x, wv = t >> 6, lane = t & 63;
    size_t row = (size_t)blockIdx.x * 4 + wv;
    int b = (int)(row >> 11);  // S = 2048
    float scale2 = rsqrtf(accum[4 + b] * (1.f / DIMN) + EPSF);
    const float4* xr = (const float4*)(x + row * DIMN);
    const float4* tr = (const float4*)(t3n + (size_t)b * DIMN);
    float4 e[8], y[8];
    float ss = 0.f;
    #pragma unroll
    for (int k = 0; k < 8; k++) {
        int idx = k * 64 + lane;
        float4 tv = tr[idx];
        float4 xv = xr[idx];
        e[k].x = tv.x * scale2; e[k].y = tv.y * scale2;
        e[k].z = tv.z * scale2; e[k].w = tv.w * scale2;
        y[k].x = xv.x + 0.05f * e[k].x; y[k].y = xv.y + 0.05f * e[k].y;
        y[k].z = xv.z + 0.05f * e[k].z; y[k].w = xv.w + 0.05f * e[k].w;
        ss += dot4(y[k], y[k]);
    }
    float rs = rsqrtf(wsum(ss) * (1.f / DIMN) + EPSF);
    float4* xo = (float4*)(xa + row * DIMN);
    float4* uo = (float4*)(ue + row * DIMN);
    #pragma unroll
    for (int k = 0; k < 8; k++) {
        int idx = k * 64 + lane;
        float4 nv = ((const float4*)nw)[idx];
        float4 o;
        o.x = y[k].x * rs * nv.x; o.y = y[k].y * rs * nv.y;
        o.z = y[k].z * rs * nv.z; o.w = y[k].w * rs * nv.w;
        xo[idx] = o;
        uo[idx] = e[k];
    }
}

extern "C" void kernel_launch(void* const* d_in, const int* in_sizes, int n_in,
                              void* d_out, int out_size, void* d_ws, size_t ws_size,
                              hipStream_t stream)
{
    (void)in_sizes; (void)n_in; (void)out_size; (void)ws_size;
    const float* x     = (const float*)d_in[0];
    const float* epi   = (const float*)d_in[1];
    const float* ale   = (const float*)d_in[2];
    const float* ood   = (const float*)d_in[3];
    const float* cunc  = (const float*)d_in[4];
    const float* ece   = (const float*)d_in[5];
    const float* moral = (const float*)d_in[6];
    const float* spw   = (const float*)d_in[7];
    const float* spb   = (const float*)d_in[8];
    const float* ipw   = (const float*)d_in[9];
    const float* ipb   = (const float*)d_in[10];
    const float* outw  = (const float*)d_in[11];
    const float* outb  = (const float*)d_in[12];
    const float* chw1  = (const float*)d_in[13];
    const float* chb1  = (const float*)d_in[14];
    const float* chw2  = (const float*)d_in[15];
    const float* chb2  = (const float*)d_in[16];
    const float* sumw1 = (const float*)d_in[17];
    const float* sumb1 = (const float*)d_in[18];
    const float* rms1  = (const float*)d_in[19];
    const float* sww1  = (const float*)d_in[20];
    const float* sww3  = (const float*)d_in[21];
    const float* sww2  = (const float*)d_in[22];
    const float* sumw2 = (const float*)d_in[23];
    const float* sumb2 = (const float*)d_in[24];
    const float* rms2  = (const float*)d_in[25];
    const float* normw = (const float*)d_in[26];

    float* out  = (float*)d_out;
    float* xa   = out;                                   // [4,2048,2048]
    float* conf = out + (size_t)BB * SSEQ * DIMN;        // [4]
    float* sig  = conf + BB;                             // [4,6]
    float* ue   = sig + BB * NSIG;                       // [4,2048,2048]

    float* ws    = (float*)d_ws;
    float* us    = ws;              // 1024
    float* t1n   = ws + 1024;       // 8192
    float* h     = ws + 9216;       // 16384
    float* t2    = ws + 25600;      // 8192
    float* t3n   = ws + 33792;      // 8192
    float* accum = ws + 41984;      // 8 (sumsq1[4], sumsq2[4])

    kA_front  <<<1, 256, 0, stream>>>(epi, ale, ood, cunc, ece, moral,
                                      ipw, ipb, spw, spb, chw1, chb1, chw2, chb2,
                                      outw, outb, us, conf, sig, accum);
    k2_sumproj<<<512, 256, 0, stream>>>(us, sumw1, sumb1, rms1, t1n, accum);
    k3_swiglu <<<1024, 256, 0, stream>>>(t1n, sww1, sww3, accum, h);
    k4_down   <<<512, 256, 0, stream>>>(h, sww2, t2);
    k5_out    <<<512, 256, 0, stream>>>(t2, sumw2, sumb2, rms2, t3n, accum);
    k7_final  <<<2048, 256, 0, stream>>>(x, t3n, accum, normw, xa, ue);
}

// Round 3
// 356.560 us; speedup vs baseline: 1.7092x; 1.7092x over previous
//
#include <hip/hip_runtime.h>
#include <math.h>

#define DIMN 2048
#define HDIM 256
#define NSIG 6
#define NHEADS 4
#define HEADDIM 64
#define SWHID 4096
#define BB 4
#define SSEQ 2048
#define EPSF 1e-6f

__device__ __forceinline__ float wsum(float v) {
    #pragma unroll
    for (int m = 1; m < 64; m <<= 1) v += __shfl_xor(v, m, 64);
    return v;
}

__device__ __forceinline__ float dot4(float4 a, float4 b) {
    return a.x*b.x + a.y*b.y + a.z*b.z + a.w*b.w;
}

// K0: A[r] = dot(ipw[r,:], sp_w); C[r] = dot(ipw[r,:], sp_b) + ipb[r]
// (rank-1 fold of signal_proj into in_proj). 192 blocks x 4 waves = 768 rows.
// Also zeroes accum.
__global__ __launch_bounds__(256) void k0_ac(
    const float* __restrict__ ipw, const float* __restrict__ ipb,
    const float* __restrict__ spw, const float* __restrict__ spb,
    float* __restrict__ A, float* __restrict__ C, float* __restrict__ accum)
{
    int t = threadIdx.x, wv = t >> 6, lane = t & 63;
    if (blockIdx.x == 0 && t < 8) accum[t] = 0.f;
    int r = blockIdx.x * 4 + wv;
    float4 w  = ((const float4*)(ipw + (size_t)r * HDIM))[lane];
    float4 a4 = ((const float4*)spw)[lane];
    float4 b4 = ((const float4*)spb)[lane];
    float aa = wsum(dot4(w, a4));
    float cc = wsum(dot4(w, b4));
    if (lane == 0) { A[r] = aa; C[r] = cc + ipb[r]; }
}

// kB: tiny single-block front-end via Gram decomposition.
// scores(b,h,qi,ki) = (gAA*sq*sk + gAC*sq + gCA*sk + gCC)/8
// obar(b,m) = sum_ki aBar(b,h(m),ki) * (sig(b,ki)*A[512+m] + C[512+m])
// Only ~7KB of global reads; all batches processed in parallel.
__global__ __launch_bounds__(256) void kB_front(
    const float* __restrict__ epi, const float* __restrict__ ale,
    const float* __restrict__ ood, const float* __restrict__ cunc,
    const float* __restrict__ ece, const float* __restrict__ moral,
    const float* __restrict__ chw1, const float* __restrict__ chb1,
    const float* __restrict__ chw2, const float* __restrict__ chb2,
    const float* __restrict__ A, const float* __restrict__ C,
    float* __restrict__ obar, float* __restrict__ out_conf,
    float* __restrict__ out_sig)
{
    __shared__ float sA[768], sC[768];
    __shared__ float sSig[BB][NSIG];
    __shared__ float sGram[NHEADS][4];
    __shared__ float sAtt[BB][NHEADS][NSIG][NSIG];
    __shared__ float sBar[BB][NHEADS][NSIG];
    __shared__ float sRedW[BB][4];
    int t = threadIdx.x, wv = t >> 6, lane = t & 63;

    for (int r = t; r < 768; r += 256) { sA[r] = A[r]; sC[r] = C[r]; }

    // signals: wave wv handles batch b = wv
    {
        int b = wv;
        float se = wsum(epi[b * 64 + lane]) * (1.f / 64.f);
        float sa = wsum(ale[b * 64 + lane]) * (1.f / 64.f);
        if (lane == 0) {
            sSig[b][0] = se; sSig[b][1] = sa;
            sSig[b][2] = ood[b]; sSig[b][3] = cunc[b];
            sSig[b][4] = ece[0]; sSig[b][5] = moral[b];
            #pragma unroll
            for (int k = 0; k < NSIG; k++) out_sig[b * NSIG + k] = sSig[b][k];
        }
    }
    __syncthreads();

    // per-head Gram scalars: wave wv = head
    {
        int h = wv;
        float aq = sA[h * 64 + lane],       cq = sC[h * 64 + lane];
        float ak = sA[256 + h * 64 + lane], ck = sC[256 + h * 64 + lane];
        float g0 = wsum(aq * ak);
        float g1 = wsum(aq * ck);
        float g2 = wsum(cq * ak);
        float g3 = wsum(cq * ck);
        if (lane == 0) { sGram[h][0] = g0; sGram[h][1] = g1; sGram[h][2] = g2; sGram[h][3] = g3; }
    }

    // confidence head: Linear(6,256) -> exact GELU -> Linear(256,1) -> sigmoid
    {
        float c1[NSIG];
        #pragma unroll
        for (int j = 0; j < NSIG; j++) c1[j] = chw1[t * NSIG + j];
        float cb = chb1[t], cw2 = chw2[t];
        #pragma unroll
        for (int b = 0; b < BB; b++) {
            float z = cb;
            #pragma unroll
            for (int j = 0; j < NSIG; j++) z += sSig[b][j] * c1[j];
            float g = 0.5f * z * (1.f + erff(z * 0.70710678118654752f));
            float v = wsum(g * cw2);
            if (lane == 0) sRedW[b][wv] = v;
        }
    }
    __syncthreads();
    if (t < BB) {
        float s = sRedW[t][0] + sRedW[t][1] + sRedW[t][2] + sRedW[t][3] + chb2[0];
        out_conf[t] = 1.f / (1.f + expf(-s));
    }

    // scores + softmax: 96 threads, one (b,h,qi) each
    if (t < 96) {
        int b = t / 24, r = t % 24, h = r / 6, qi = r % 6;
        float sq = sSig[b][qi];
        float g0 = sGram[h][0], g1 = sGram[h][1], g2 = sGram[h][2], g3 = sGram[h][3];
        float sc[NSIG]; float mx = -1e30f;
        #pragma unroll
        for (int ki = 0; ki < NSIG; ki++) {
            float sk = sSig[b][ki];
            float s = (g0 * sq * sk + g1 * sq + g2 * sk + g3) * 0.125f;
            sc[ki] = s; mx = fmaxf(mx, s);
        }
        float den = 0;
        #pragma unroll
        for (int ki = 0; ki < NSIG; ki++) { sc[ki] = expf(sc[ki] - mx); den += sc[ki]; }
        float inv = 1.f / den;
        #pragma unroll
        for (int ki = 0; ki < NSIG; ki++) sAtt[b][h][qi][ki] = sc[ki] * inv;
    }
    __syncthreads();

    // aBar(b,h,ki) = (1/6) sum_qi att(b,h,qi,ki)
    if (t < 96) {
        int b = t / 24, r = t % 24, h = r / 6, ki = r % 6;
        float s = 0;
        #pragma unroll
        for (int qi = 0; qi < NSIG; qi++) s += sAtt[b][h][qi][ki];
        sBar[b][h][ki] = s * (1.f / 6.f);
    }
    __syncthreads();

    // obar(b,m) = sum_ki aBar(b,h,ki) * (sig(b,ki)*A[512+m] + C[512+m])
    {
        float am = sA[512 + t], cm = sC[512 + t];
        int h = t >> 6;
        #pragma unroll
        for (int b = 0; b < BB; b++) {
            float o = 0;
            #pragma unroll
            for (int ki = 0; ki < NSIG; ki++)
                o += sBar[b][h][ki] * (sSig[b][ki] * am + cm);
            obar[b * HDIM + t] = o;
        }
    }
}

// kC: unc_summary[b][m] = dot(obar[b], out_w[m,:]) + out_b[m]
__global__ __launch_bounds__(256) void kC_us(
    const float* __restrict__ obar, const float* __restrict__ outw,
    const float* __restrict__ outb, float* __restrict__ us)
{
    int t = threadIdx.x, wv = t >> 6, lane = t & 63;
    int m = blockIdx.x * 4 + wv;
    float4 w = ((const float4*)(outw + (size_t)m * HDIM))[lane];
    float acc[BB];
    #pragma unroll
    for (int b = 0; b < BB; b++) {
        float4 o = ((const float4*)(obar + b * HDIM))[lane];
        acc[b] = dot4(w, o);
    }
    #pragma unroll
    for (int b = 0; b < BB; b++) acc[b] = wsum(acc[b]);
    if (lane == 0) {
        float ob = outb[m];
        #pragma unroll
        for (int b = 0; b < BB; b++) us[b * HDIM + m] = acc[b] + ob;
    }
}

// K2: t1n[b][d] = (dot(us[b], sum_w1[d,:]) + sum_b1[d]) * rms1_w[d]; accum[b] += pre^2
__global__ __launch_bounds__(256) void k2_sumproj(
    const float* __restrict__ us, const float* __restrict__ w1,
    const float* __restrict__ b1, const float* __restrict__ rw1,
    float* __restrict__ t1n, float* __restrict__ accum)
{
    __shared__ float bsq[BB];
    int t = threadIdx.x, wv = t >> 6, lane = t & 63;
    if (t < BB) bsq[t] = 0.f;
    __syncthreads();
    int d = blockIdx.x * 4 + wv;
    float4 w = ((const float4*)(w1 + (size_t)d * HDIM))[lane];
    float acc[BB];
    #pragma unroll
    for (int b = 0; b < BB; b++) {
        float4 u = ((const float4*)(us + b * HDIM))[lane];
        acc[b] = dot4(w, u);
    }
    #pragma unroll
    for (int b = 0; b < BB; b++) acc[b] = wsum(acc[b]);
    if (lane == 0) {
        #pragma unroll
        for (int b = 0; b < BB; b++) {
            float v = acc[b] + b1[d];
            atomicAdd(&bsq[b], v * v);
            t1n[b * DIMN + d] = v * rw1[d];
        }
    }
    __syncthreads();
    if (t < BB) atomicAdd(&accum[t], bsq[t]);
}

// K3: h[b][j] = silu(s1*dot(t1n[b], sw_w1[j,:])) * (s1*dot(t1n[b], sw_w3[j,:]))
__global__ __launch_bounds__(256) void k3_swiglu(
    const float* __restrict__ t1n, const float* __restrict__ sw1,
    const float* __restrict__ sw3, const float* __restrict__ accum,
    float* __restrict__ h)
{
    __shared__ __align__(16) float sT[BB * DIMN];
    int t = threadIdx.x, wv = t >> 6, lane = t & 63;
    #pragma unroll
    for (int k = 0; k < 8; k++)
        ((float4*)sT)[k * 256 + t] = ((const float4*)t1n)[k * 256 + t];
    __syncthreads();
    int j = blockIdx.x * 4 + wv;
    const float4* r1 = (const float4*)(sw1 + (size_t)j * DIMN);
    const float4* r3 = (const float4*)(sw3 + (size_t)j * DIMN);
    float acc1[BB] = {0,0,0,0}, acc3[BB] = {0,0,0,0};
    #pragma unroll
    for (int it = 0; it < 8; it++) {
        float4 w1 = r1[it * 64 + lane];
        float4 w3 = r3[it * 64 + lane];
        #pragma unroll
        for (int b = 0; b < BB; b++) {
            float4 tv = ((const float4*)(sT + b * DIMN))[it * 64 + lane];
            acc1[b] += dot4(w1, tv);
            acc3[b] += dot4(w3, tv);
        }
    }
    #pragma unroll
    for (int b = 0; b < BB; b++) { acc1[b] = wsum(acc1[b]); acc3[b] = wsum(acc3[b]); }
    if (lane == 0) {
        #pragma unroll
        for (int b = 0; b < BB; b++) {
            float s = rsqrtf(accum[b] * (1.f / DIMN) + EPSF);
            float a = acc1[b] * s;
            float sil = a / (1.f + expf(-a));
            h[b * SWHID + j] = sil * (acc3[b] * s);
        }
    }
}

// K4: t2[b][d] = dot(h[b], sw_w2[d,:])
__global__ __launch_bounds__(256) void k4_down(
    const float* __restrict__ h, const float* __restrict__ sw2,
    float* __restrict__ t2)
{
    __shared__ __align__(16) float sH[BB * SWHID];  // 64 KiB
    int t = threadIdx.x, wv = t >> 6, lane = t & 63;
    #pragma unroll
    for (int k = 0; k < 16; k++)
        ((float4*)sH)[k * 256 + t] = ((const float4*)h)[k * 256 + t];
    __syncthreads();
    int d = blockIdx.x * 4 + wv;
    const float4* wr = (const float4*)(sw2 + (size_t)d * SWHID);
    float acc[BB] = {0,0,0,0};
    #pragma unroll
    for (int it = 0; it < 16; it++) {
        float4 w = wr[it * 64 + lane];
        #pragma unroll
        for (int b = 0; b < BB; b++) {
            float4 hv = ((const float4*)(sH + b * SWHID))[it * 64 + lane];
            acc[b] += dot4(w, hv);
        }
    }
    #pragma unroll
    for (int b = 0; b < BB; b++) acc[b] = wsum(acc[b]);
    if (lane == 0) {
        #pragma unroll
        for (int b = 0; b < BB; b++) t2[b * DIMN + d] = acc[b];
    }
}

// K5: t3n[b][d] = (dot(t2[b], sum_w2[d,:]) + sum_b2[d]) * rms2_w[d]; accum[4+b] += pre^2
__global__ __launch_bounds__(256) void k5_out(
    const float* __restrict__ t2, const float* __restrict__ w2,
    const float* __restrict__ b2, const float* __restrict__ rw2,
    float* __restrict__ t3n, float* __restrict__ accum)
{
    __shared__ __align__(16) float sT[BB * DIMN];
    __shared__ float bsq[BB];
    int t = threadIdx.x, wv = t >> 6, lane = t & 63;
    if (t < BB) bsq[t] = 0.f;
    #pragma unroll
    for (int k = 0; k < 8; k++)
        ((float4*)sT)[k * 256 + t] = ((const float4*)t2)[k * 256 + t];
    __syncthreads();
    int d = blockIdx.x * 4 + wv;
    const float4* wr = (const float4*)(w2 + (size_t)d * DIMN);
    float acc[BB] = {0,0,0,0};
    #pragma unroll
    for (int it = 0; it < 8; it++) {
        float4 w = wr[it * 64 + lane];
        #pragma unroll
        for (int b = 0; b < BB; b++) {
            float4 tv = ((const float4*)(sT + b * DIMN))[it * 64 + lane];
            acc[b] += dot4(w, tv);
        }
    }
    #pragma unroll
    for (int b = 0; b < BB; b++) acc[b] = wsum(acc[b]);
    if (lane == 0) {
        #pragma unroll
        for (int b = 0; b < BB; b++) {
            float v = acc[b] + b2[d];
            atomicAdd(&bsq[b], v * v);
            t3n[b * DIMN + d] = v * rw2[d];
        }
    }
    __syncthreads();
    if (t < BB) atomicAdd(&accum[4 + t], bsq[t]);
}

// K7: one wave per token row. e = t3n*scale2 (= unc_embedding), y = x + 0.05*e,
//     x_aware = rmsnorm(y)*norm_w. No LDS, no __syncthreads.
__global__ __launch_bounds__(256) void k7_final(
    const float* __restrict__ x, const float* __restrict__ t3n,
    const float* __restrict__ accum, const float* __restrict__ nw,
    float* __restrict__ xa, float* __restrict__ ue)
{
    int t = threadIdx.x, wv = t >> 6, lane = t & 63;
    size_t row = (size_t)blockIdx.x * 4 + wv;
    int b = (int)(row >> 11);  // S = 2048
    float scale2 = rsqrtf(accum[4 + b] * (1.f / DIMN) + EPSF);
    const float4* xr = (const float4*)(x + row * DIMN);
    const float4* tr = (const float4*)(t3n + (size_t)b * DIMN);
    float4 e[8], y[8];
    float ss = 0.f;
    #pragma unroll
    for (int k = 0; k < 8; k++) {
        int idx = k * 64 + lane;
        float4 tv = tr[idx];
        float4 xv = xr[idx];
        e[k].x = tv.x * scale2; e[k].y = tv.y * scale2;
        e[k].z = tv.z * scale2; e[k].w = tv.w * scale2;
        y[k].x = xv.x + 0.05f * e[k].x; y[k].y = xv.y + 0.05f * e[k].y;
        y[k].z = xv.z + 0.05f * e[k].z; y[k].w = xv.w + 0.05f * e[k].w;
        ss += dot4(y[k], y[k]);
    }
    float rs = rsqrtf(wsum(ss) * (1.f / DIMN) + EPSF);
    float4* xo = (float4*)(xa + row * DIMN);
    float4* uo = (float4*)(ue + row * DIMN);
    #pragma unroll
    for (int k = 0; k < 8; k++) {
        int idx = k * 64 + lane;
        float4 nv = ((const float4*)nw)[idx];
        float4 o;
        o.x = y[k].x * rs * nv.x; o.y = y[k].y * rs * nv.y;
        o.z = y[k].z * rs * nv.z; o.w = y[k].w * rs * nv.w;
        xo[idx] = o;
        uo[idx] = e[k];
    }
}

extern "C" void kernel_launch(void* const* d_in, const int* in_sizes, int n_in,
                              void* d_out, int out_size, void* d_ws, size_t ws_size,
                              hipStream_t stream)
{
    (void)in_sizes; (void)n_in; (void)out_size; (void)ws_size;
    const float* x     = (const float*)d_in[0];
    const float* epi   = (const float*)d_in[1];
    const float* ale   = (const float*)d_in[2];
    const float* ood   = (const float*)d_in[3];
    const float* cunc  = (const float*)d_in[4];
    const float* ece   = (const float*)d_in[5];
    const float* moral = (const float*)d_in[6];
    const float* spw   = (const float*)d_in[7];
    const float* spb   = (const float*)d_in[8];
    const float* ipw   = (const float*)d_in[9];
    const float* ipb   = (const float*)d_in[10];
    const float* outw  = (const float*)d_in[11];
    const float* outb  = (const float*)d_in[12];
    const float* chw1  = (const float*)d_in[13];
    const float* chb1  = (const float*)d_in[14];
    const float* chw2  = (const float*)d_in[15];
    const float* chb2  = (const float*)d_in[16];
    const float* sumw1 = (const float*)d_in[17];
    const float* sumb1 = (const float*)d_in[18];
    const float* rms1  = (const float*)d_in[19];
    const float* sww1  = (const float*)d_in[20];
    const float* sww3  = (const float*)d_in[21];
    const float* sww2  = (const float*)d_in[22];
    const float* sumw2 = (const float*)d_in[23];
    const float* sumb2 = (const float*)d_in[24];
    const float* rms2  = (const float*)d_in[25];
    const float* normw = (const float*)d_in[26];

    float* out  = (float*)d_out;
    float* xa   = out;                                   // [4,2048,2048]
    float* conf = out + (size_t)BB * SSEQ * DIMN;        // [4]
    float* sig  = conf + BB;                             // [4,6]
    float* ue   = sig + BB * NSIG;                       // [4,2048,2048]

    float* ws    = (float*)d_ws;
    float* A     = ws;              // 768
    float* C     = ws + 768;        // 768
    float* obar  = ws + 1536;       // 1024
    float* us    = ws + 2560;       // 1024
    float* t1n   = ws + 3584;       // 8192
    float* h     = ws + 11776;      // 16384
    float* t2    = ws + 28160;      // 8192
    float* t3n   = ws + 36352;      // 8192
    float* accum = ws + 44544;      // 8 (sumsq1[4], sumsq2[4])

    k0_ac   <<<192, 256, 0, stream>>>(ipw, ipb, spw, spb, A, C, accum);
    kB_front<<<1, 256, 0, stream>>>(epi, ale, ood, cunc, ece, moral,
                                    chw1, chb1, chw2, chb2, A, C, obar, conf, sig);
    kC_us   <<<64, 256, 0, stream>>>(obar, outw, outb, us);
    k2_sumproj<<<512, 256, 0, stream>>>(us, sumw1, sumb1, rms1, t1n, accum);
    k3_swiglu <<<1024, 256, 0, stream>>>(t1n, sww1, sww3, accum, h);
    k4_down   <<<512, 256, 0, stream>>>(h, sww2, t2);
    k5_out    <<<512, 256, 0, stream>>>(t2, sumw2, sumb2, rms2, t3n, accum);
    k7_final  <<<2048, 256, 0, stream>>>(x, t3n, accum, normw, xa, ue);
}

// Round 4
// 353.220 us; speedup vs baseline: 1.7253x; 1.0095x over previous
//
#include <hip/hip_runtime.h>
#include <math.h>

#define DIMN 2048
#define HDIM 256
#define NSIG 6
#define NHEADS 4
#define HEADDIM 64
#define SWHID 4096
#define BB 4
#define SSEQ 2048
#define EPSF 1e-6f

__device__ __forceinline__ float wsum(float v) {
    #pragma unroll
    for (int m = 1; m < 64; m <<= 1) v += __shfl_xor(v, m, 64);
    return v;
}

__device__ __forceinline__ float dot4(float4 a, float4 b) {
    return a.x*b.x + a.y*b.y + a.z*b.z + a.w*b.w;
}

// K0: A[r] = dot(ipw[r,:], sp_w); C[r] = dot(ipw[r,:], sp_b) + ipb[r]
// (rank-1 fold of signal_proj into in_proj). 192 blocks x 4 waves = 768 rows.
// Also zeroes accum.
__global__ __launch_bounds__(256) void k0_ac(
    const float* __restrict__ ipw, const float* __restrict__ ipb,
    const float* __restrict__ spw, const float* __restrict__ spb,
    float* __restrict__ A, float* __restrict__ C, float* __restrict__ accum)
{
    int t = threadIdx.x, wv = t >> 6, lane = t & 63;
    if (blockIdx.x == 0 && t < 8) accum[t] = 0.f;
    int r = blockIdx.x * 4 + wv;
    float4 w  = ((const float4*)(ipw + (size_t)r * HDIM))[lane];
    float4 a4 = ((const float4*)spw)[lane];
    float4 b4 = ((const float4*)spb)[lane];
    float aa = wsum(dot4(w, a4));
    float cc = wsum(dot4(w, b4));
    if (lane == 0) { A[r] = aa; C[r] = cc + ipb[r]; }
}

// kUV: fold out_w through the V-projection.
// U[n][h] = sum_{m in head h} outw[n][m] * A[512+m]
// V[n][h] = sum_{m in head h} outw[n][m] * C[512+m]
// 64 blocks x 4 waves; wave = one n; segmented 16-lane reduction (h = lane/16).
__global__ __launch_bounds__(256) void kUV(
    const float* __restrict__ A, const float* __restrict__ C,
    const float* __restrict__ outw,
    float* __restrict__ U, float* __restrict__ V)
{
    int t = threadIdx.x, wv = t >> 6, lane = t & 63;
    int n = blockIdx.x * 4 + wv;
    float4 w = ((const float4*)(outw + (size_t)n * HDIM))[lane];
    float4 a = ((const float4*)(A + 512))[lane];
    float4 c = ((const float4*)(C + 512))[lane];
    float pu = dot4(w, a), pv = dot4(w, c);
    #pragma unroll
    for (int m = 1; m < 16; m <<= 1) {
        pu += __shfl_xor(pu, m, 64);
        pv += __shfl_xor(pv, m, 64);
    }
    if ((lane & 15) == 0) {
        int h = lane >> 4;
        U[n * NHEADS + h] = pu;
        V[n * NHEADS + h] = pv;
    }
}

// kB: tiny single-block front-end.
// scores(b,h,qi,ki) = (gAA*sq*sk + gAC*sq + gCA*sk + gCC)/8 via per-head Gram
// scalars; softmax; aBar = column-mean of att (token mean commutes with the
// linear out-proj); then us[b][n] = outb[n] + sum_{h,ki} aBar*(sig*U + V).
// ~20 KB of global reads total.
__global__ __launch_bounds__(256) void kB_front(
    const float* __restrict__ epi, const float* __restrict__ ale,
    const float* __restrict__ ood, const float* __restrict__ cunc,
    const float* __restrict__ ece, const float* __restrict__ moral,
    const float* __restrict__ chw1, const float* __restrict__ chb1,
    const float* __restrict__ chw2, const float* __restrict__ chb2,
    const float* __restrict__ A, const float* __restrict__ C,
    const float* __restrict__ U, const float* __restrict__ V,
    const float* __restrict__ outb,
    float* __restrict__ us, float* __restrict__ out_conf,
    float* __restrict__ out_sig)
{
    __shared__ float sA[512], sC[512];
    __shared__ float sSig[BB][NSIG];
    __shared__ float sGram[NHEADS][4];
    __shared__ float sAtt[BB][NHEADS][NSIG][NSIG];
    __shared__ float sBar[BB][NHEADS][NSIG];
    __shared__ float sRedW[BB][4];
    int t = threadIdx.x, wv = t >> 6, lane = t & 63;

    for (int r = t; r < 512; r += 256) { sA[r] = A[r]; sC[r] = C[r]; }

    // signals: wave wv handles batch b = wv
    {
        int b = wv;
        float se = wsum(epi[b * 64 + lane]) * (1.f / 64.f);
        float sa = wsum(ale[b * 64 + lane]) * (1.f / 64.f);
        if (lane == 0) {
            sSig[b][0] = se; sSig[b][1] = sa;
            sSig[b][2] = ood[b]; sSig[b][3] = cunc[b];
            sSig[b][4] = ece[0]; sSig[b][5] = moral[b];
            #pragma unroll
            for (int k = 0; k < NSIG; k++) out_sig[b * NSIG + k] = sSig[b][k];
        }
    }
    __syncthreads();

    // per-head Gram scalars: wave wv = head
    {
        int h = wv;
        float aq = sA[h * 64 + lane],       cq = sC[h * 64 + lane];
        float ak = sA[256 + h * 64 + lane], ck = sC[256 + h * 64 + lane];
        float g0 = wsum(aq * ak);
        float g1 = wsum(aq * ck);
        float g2 = wsum(cq * ak);
        float g3 = wsum(cq * ck);
        if (lane == 0) { sGram[h][0] = g0; sGram[h][1] = g1; sGram[h][2] = g2; sGram[h][3] = g3; }
    }

    // confidence head: Linear(6,256) -> exact GELU -> Linear(256,1) -> sigmoid
    {
        float c1[NSIG];
        #pragma unroll
        for (int j = 0; j < NSIG; j++) c1[j] = chw1[t * NSIG + j];
        float cb = chb1[t], cw2 = chw2[t];
        #pragma unroll
        for (int b = 0; b < BB; b++) {
            float z = cb;
            #pragma unroll
            for (int j = 0; j < NSIG; j++) z += sSig[b][j] * c1[j];
            float g = 0.5f * z * (1.f + erff(z * 0.70710678118654752f));
            float v = wsum(g * cw2);
            if (lane == 0) sRedW[b][wv] = v;
        }
    }
    __syncthreads();
    if (t < BB) {
        float s = sRedW[t][0] + sRedW[t][1] + sRedW[t][2] + sRedW[t][3] + chb2[0];
        out_conf[t] = 1.f / (1.f + expf(-s));
    }

    // scores + softmax: 96 threads, one (b,h,qi) each
    if (t < 96) {
        int b = t / 24, r = t % 24, h = r / 6, qi = r % 6;
        float sq = sSig[b][qi];
        float g0 = sGram[h][0], g1 = sGram[h][1], g2 = sGram[h][2], g3 = sGram[h][3];
        float sc[NSIG]; float mx = -1e30f;
        #pragma unroll
        for (int ki = 0; ki < NSIG; ki++) {
            float sk = sSig[b][ki];
            float s = (g0 * sq * sk + g1 * sq + g2 * sk + g3) * 0.125f;
            sc[ki] = s; mx = fmaxf(mx, s);
        }
        float den = 0;
        #pragma unroll
        for (int ki = 0; ki < NSIG; ki++) { sc[ki] = expf(sc[ki] - mx); den += sc[ki]; }
        float inv = 1.f / den;
        #pragma unroll
        for (int ki = 0; ki < NSIG; ki++) sAtt[b][h][qi][ki] = sc[ki] * inv;
    }
    __syncthreads();

    // aBar(b,h,ki) = (1/6) sum_qi att(b,h,qi,ki)
    if (t < 96) {
        int b = t / 24, r = t % 24, h = r / 6, ki = r % 6;
        float s = 0;
        #pragma unroll
        for (int qi = 0; qi < NSIG; qi++) s += sAtt[b][h][qi][ki];
        sBar[b][h][ki] = s * (1.f / 6.f);
    }
    __syncthreads();

    // us[b][n] = outb[n] + sum_{h,ki} aBar(b,h,ki)*(sig(b,ki)*U[n][h] + V[n][h])
    {
        float uu[NHEADS], vv[NHEADS];
        #pragma unroll
        for (int h = 0; h < NHEADS; h++) {
            uu[h] = U[t * NHEADS + h];
            vv[h] = V[t * NHEADS + h];
        }
        float ob = outb[t];
        #pragma unroll
        for (int b = 0; b < BB; b++) {
            float acc = ob;
            #pragma unroll
            for (int h = 0; h < NHEADS; h++) {
                float hu = 0, hv = 0;
                #pragma unroll
                for (int ki = 0; ki < NSIG; ki++) {
                    hu += sBar[b][h][ki] * sSig[b][ki];
                    hv += sBar[b][h][ki];
                }
                acc += hu * uu[h] + hv * vv[h];
            }
            us[b * HDIM + t] = acc;
        }
    }
}

// K2: t1n[b][d] = (dot(us[b], sum_w1[d,:]) + sum_b1[d]) * rms1_w[d]; accum[b] += pre^2
__global__ __launch_bounds__(256) void k2_sumproj(
    const float* __restrict__ us, const float* __restrict__ w1,
    const float* __restrict__ b1, const float* __restrict__ rw1,
    float* __restrict__ t1n, float* __restrict__ accum)
{
    __shared__ float bsq[BB];
    int t = threadIdx.x, wv = t >> 6, lane = t & 63;
    if (t < BB) bsq[t] = 0.f;
    __syncthreads();
    int d = blockIdx.x * 4 + wv;
    float4 w = ((const float4*)(w1 + (size_t)d * HDIM))[lane];
    float acc[BB];
    #pragma unroll
    for (int b = 0; b < BB; b++) {
        float4 u = ((const float4*)(us + b * HDIM))[lane];
        acc[b] = dot4(w, u);
    }
    #pragma unroll
    for (int b = 0; b < BB; b++) acc[b] = wsum(acc[b]);
    if (lane == 0) {
        #pragma unroll
        for (int b = 0; b < BB; b++) {
            float v = acc[b] + b1[d];
            atomicAdd(&bsq[b], v * v);
            t1n[b * DIMN + d] = v * rw1[d];
        }
    }
    __syncthreads();
    if (t < BB) atomicAdd(&accum[t], bsq[t]);
}

// K3: h[b][j] = silu(s1*dot(t1n[b], sw_w1[j,:])) * (s1*dot(t1n[b], sw_w3[j,:]))
__global__ __launch_bounds__(256) void k3_swiglu(
    const float* __restrict__ t1n, const float* __restrict__ sw1,
    const float* __restrict__ sw3, const float* __restrict__ accum,
    float* __restrict__ h)
{
    __shared__ __align__(16) float sT[BB * DIMN];
    int t = threadIdx.x, wv = t >> 6, lane = t & 63;
    #pragma unroll
    for (int k = 0; k < 8; k++)
        ((float4*)sT)[k * 256 + t] = ((const float4*)t1n)[k * 256 + t];
    __syncthreads();
    int j = blockIdx.x * 4 + wv;
    const float4* r1 = (const float4*)(sw1 + (size_t)j * DIMN);
    const float4* r3 = (const float4*)(sw3 + (size_t)j * DIMN);
    float acc1[BB] = {0,0,0,0}, acc3[BB] = {0,0,0,0};
    #pragma unroll
    for (int it = 0; it < 8; it++) {
        float4 w1 = r1[it * 64 + lane];
        float4 w3 = r3[it * 64 + lane];
        #pragma unroll
        for (int b = 0; b < BB; b++) {
            float4 tv = ((const float4*)(sT + b * DIMN))[it * 64 + lane];
            acc1[b] += dot4(w1, tv);
            acc3[b] += dot4(w3, tv);
        }
    }
    #pragma unroll
    for (int b = 0; b < BB; b++) { acc1[b] = wsum(acc1[b]); acc3[b] = wsum(acc3[b]); }
    if (lane == 0) {
        #pragma unroll
        for (int b = 0; b < BB; b++) {
            float s = rsqrtf(accum[b] * (1.f / DIMN) + EPSF);
            float a = acc1[b] * s;
            float sil = a / (1.f + expf(-a));
            h[b * SWHID + j] = sil * (acc3[b] * s);
        }
    }
}

// K4: t2[b][d] = dot(h[b], sw_w2[d,:])
__global__ __launch_bounds__(256) void k4_down(
    const float* __restrict__ h, const float* __restrict__ sw2,
    float* __restrict__ t2)
{
    __shared__ __align__(16) float sH[BB * SWHID];  // 64 KiB
    int t = threadIdx.x, wv = t >> 6, lane = t & 63;
    #pragma unroll
    for (int k = 0; k < 16; k++)
        ((float4*)sH)[k * 256 + t] = ((const float4*)h)[k * 256 + t];
    __syncthreads();
    int d = blockIdx.x * 4 + wv;
    const float4* wr = (const float4*)(sw2 + (size_t)d * SWHID);
    float acc[BB] = {0,0,0,0};
    #pragma unroll
    for (int it = 0; it < 16; it++) {
        float4 w = wr[it * 64 + lane];
        #pragma unroll
        for (int b = 0; b < BB; b++) {
            float4 hv = ((const float4*)(sH + b * SWHID))[it * 64 + lane];
            acc[b] += dot4(w, hv);
        }
    }
    #pragma unroll
    for (int b = 0; b < BB; b++) acc[b] = wsum(acc[b]);
    if (lane == 0) {
        #pragma unroll
        for (int b = 0; b < BB; b++) t2[b * DIMN + d] = acc[b];
    }
}

// K5: t3n[b][d] = (dot(t2[b], sum_w2[d,:]) + sum_b2[d]) * rms2_w[d]; accum[4+b] += pre^2
__global__ __launch_bounds__(256) void k5_out(
    const float* __restrict__ t2, const float* __restrict__ w2,
    const float* __restrict__ b2, const float* __restrict__ rw2,
    float* __restrict__ t3n, float* __restrict__ accum)
{
    __shared__ __align__(16) float sT[BB * DIMN];
    __shared__ float bsq[BB];
    int t = threadIdx.x, wv = t >> 6, lane = t & 63;
    if (t < BB) bsq[t] = 0.f;
    #pragma unroll
    for (int k = 0; k < 8; k++)
        ((float4*)sT)[k * 256 + t] = ((const float4*)t2)[k * 256 + t];
    __syncthreads();
    int d = blockIdx.x * 4 + wv;
    const float4* wr = (const float4*)(w2 + (size_t)d * DIMN);
    float acc[BB] = {0,0,0,0};
    #pragma unroll
    for (int it = 0; it < 8; it++) {
        float4 w = wr[it * 64 + lane];
        #pragma unroll
        for (int b = 0; b < BB; b++) {
            float4 tv = ((const float4*)(sT + b * DIMN))[it * 64 + lane];
            acc[b] += dot4(w, tv);
        }
    }
    #pragma unroll
    for (int b = 0; b < BB; b++) acc[b] = wsum(acc[b]);
    if (lane == 0) {
        #pragma unroll
        for (int b = 0; b < BB; b++) {
            float v = acc[b] + b2[d];
            atomicAdd(&bsq[b], v * v);
            t3n[b * DIMN + d] = v * rw2[d];
        }
    }
    __syncthreads();
    if (t < BB) atomicAdd(&accum[4 + t], bsq[t]);
}

// K7: one wave per token row. e = t3n*scale2 (= unc_embedding), y = x + 0.05*e,
//     x_aware = rmsnorm(y)*norm_w. No LDS, no __syncthreads.
__global__ __launch_bounds__(256) void k7_final(
    const float* __restrict__ x, const float* __restrict__ t3n,
    const float* __restrict__ accum, const float* __restrict__ nw,
    float* __restrict__ xa, float* __restrict__ ue)
{
    int t = threadIdx.x, wv = t >> 6, lane = t & 63;
    size_t row = (size_t)blockIdx.x * 4 + wv;
    int b = (int)(row >> 11);  // S = 2048
    float scale2 = rsqrtf(accum[4 + b] * (1.f / DIMN) + EPSF);
    const float4* xr = (const float4*)(x + row * DIMN);
    const float4* tr = (const float4*)(t3n + (size_t)b * DIMN);
    float4 e[8], y[8];
    float ss = 0.f;
    #pragma unroll
    for (int k = 0; k < 8; k++) {
        int idx = k * 64 + lane;
        float4 tv = tr[idx];
        float4 xv = xr[idx];
        e[k].x = tv.x * scale2; e[k].y = tv.y * scale2;
        e[k].z = tv.z * scale2; e[k].w = tv.w * scale2;
        y[k].x = xv.x + 0.05f * e[k].x; y[k].y = xv.y + 0.05f * e[k].y;
        y[k].z = xv.z + 0.05f * e[k].z; y[k].w = xv.w + 0.05f * e[k].w;
        ss += dot4(y[k], y[k]);
    }
    float rs = rsqrtf(wsum(ss) * (1.f / DIMN) + EPSF);
    float4* xo = (float4*)(xa + row * DIMN);
    float4* uo = (float4*)(ue + row * DIMN);
    #pragma unroll
    for (int k = 0; k < 8; k++) {
        int idx = k * 64 + lane;
        float4 nv = ((const float4*)nw)[idx];
        float4 o;
        o.x = y[k].x * rs * nv.x; o.y = y[k].y * rs * nv.y;
        o.z = y[k].z * rs * nv.z; o.w = y[k].w * rs * nv.w;
        xo[idx] = o;
        uo[idx] = e[k];
    }
}

extern "C" void kernel_launch(void* const* d_in, const int* in_sizes, int n_in,
                              void* d_out, int out_size, void* d_ws, size_t ws_size,
                              hipStream_t stream)
{
    (void)in_sizes; (void)n_in; (void)out_size; (void)ws_size;
    const float* x     = (const float*)d_in[0];
    const float* epi   = (const float*)d_in[1];
    const float* ale   = (const float*)d_in[2];
    const float* ood   = (const float*)d_in[3];
    const float* cunc  = (const float*)d_in[4];
    const float* ece   = (const float*)d_in[5];
    const float* moral = (const float*)d_in[6];
    const float* spw   = (const float*)d_in[7];
    const float* spb   = (const float*)d_in[8];
    const float* ipw   = (const float*)d_in[9];
    const float* ipb   = (const float*)d_in[10];
    const float* outw  = (const float*)d_in[11];
    const float* outb  = (const float*)d_in[12];
    const float* chw1  = (const float*)d_in[13];
    const float* chb1  = (const float*)d_in[14];
    const float* chw2  = (const float*)d_in[15];
    const float* chb2  = (const float*)d_in[16];
    const float* sumw1 = (const float*)d_in[17];
    const float* sumb1 = (const float*)d_in[18];
    const float* rms1  = (const float*)d_in[19];
    const float* sww1  = (const float*)d_in[20];
    const float* sww3  = (const float*)d_in[21];
    const float* sww2  = (const float*)d_in[22];
    const float* sumw2 = (const float*)d_in[23];
    const float* sumb2 = (const float*)d_in[24];
    const float* rms2  = (const float*)d_in[25];
    const float* normw = (const float*)d_in[26];

    float* out  = (float*)d_out;
    float* xa   = out;                                   // [4,2048,2048]
    float* conf = out + (size_t)BB * SSEQ * DIMN;        // [4]
    float* sig  = conf + BB;                             // [4,6]
    float* ue   = sig + BB * NSIG;                       // [4,2048,2048]

    float* ws    = (float*)d_ws;
    float* A     = ws;              // 768
    float* C     = ws + 768;        // 768
    float* U     = ws + 1536;       // 1024
    float* V     = ws + 2560;       // 1024
    float* us    = ws + 3584;       // 1024
    float* t1n   = ws + 4608;       // 8192
    float* h     = ws + 12800;      // 16384
    float* t2    = ws + 29184;      // 8192
    float* t3n   = ws + 37376;      // 8192
    float* accum = ws + 45568;      // 8 (sumsq1[4], sumsq2[4])

    k0_ac   <<<192, 256, 0, stream>>>(ipw, ipb, spw, spb, A, C, accum);
    kUV     <<<64, 256, 0, stream>>>(A, C, outw, U, V);
    kB_front<<<1, 256, 0, stream>>>(epi, ale, ood, cunc, ece, moral,
                                    chw1, chb1, chw2, chb2, A, C, U, V, outb,
                                    us, conf, sig);
    k2_sumproj<<<512, 256, 0, stream>>>(us, sumw1, sumb1, rms1, t1n, accum);
    k3_swiglu <<<1024, 256, 0, stream>>>(t1n, sww1, sww3, accum, h);
    k4_down   <<<512, 256, 0, stream>>>(h, sww2, t2);
    k5_out    <<<512, 256, 0, stream>>>(t2, sumw2, sumb2, rms2, t3n, accum);
    k7_final  <<<2048, 256, 0, stream>>>(x, t3n, accum, normw, xa, ue);
}